// Round 20
// baseline (79.050 us; speedup 1.0000x reference)
//
#include <hip/hip_runtime.h>
#include <math.h>

#define NPTS 2048
#define QQ 8
#define LAT 64
#define LOG2E 1.4426950408889634f
#define SQRT_LOG2E 1.2011224087864498f
#define LN2 0.6931471805599453f
#define FSTRIDE (QQ * NPTS)

typedef float v2f __attribute__((ext_vector_type(2)));

__device__ __forceinline__ float exp2_fast(float v) { return __builtin_amdgcn_exp2f(v); }
__device__ __forceinline__ float log2_fast(float v) { return __builtin_amdgcn_logf(v); }

__device__ __forceinline__ float softplus_f(float v) {
    return fmaxf(v, 0.f) + LN2 * log2_fast(1.f + exp2_fast(-fabsf(v) * LOG2E));
}

// feat (R10, unchanged): one point per wave, no LDS, no barriers.
__global__ __launch_bounds__(256) void feat_kernel(
    const float* __restrict__ x, const float* __restrict__ y,
    const float* __restrict__ W1, const float* __restrict__ b1,
    const float* __restrict__ Ww, const float* __restrict__ bw,
    const float* __restrict__ Wf, const float* __restrict__ bf,
    const float* __restrict__ Ws, const float* __restrict__ bs,
    float* __restrict__ FX, float* __restrict__ FY)
{
    const int t    = threadIdx.x;
    const int wv   = t >> 6;
    const int lane = t & 63;
    const int c    = lane & 7;
    const int q    = lane >> 3;
    const int bid  = blockIdx.x;
    const int side = bid >> 9;
    const int i    = (bid & 511) * 4 + wv;
    const float* P = side ? y : x;
    float* F = side ? FY : FX;

    const float p0 = P[i*3+0], p1 = P[i*3+1], p2 = P[i*3+2];
    const float lam = 1.0507009873554805f, lamalf = 1.7580993408473766f;

    float wa = 0.f, sa = 0.f, f0a = 0.f, f1a = 0.f, f2a = 0.f;
    #pragma unroll
    for (int it = 0; it < 8; ++it) {
        int l = it*8 + c;
        float v = fmaf(W1[l*3+0], p0, fmaf(W1[l*3+1], p1, fmaf(W1[l*3+2], p2, b1[l])));
        float e = exp2_fast(v * LOG2E);
        float h = v > 0.f ? lam * v : lamalf * (e - 1.f);
        wa  = fmaf(Ww[q*LAT + l],       h, wa);
        sa  = fmaf(Ws[q*LAT + l],       h, sa);
        f0a = fmaf(Wf[(q*3+0)*LAT + l], h, f0a);
        f1a = fmaf(Wf[(q*3+1)*LAT + l], h, f1a);
        f2a = fmaf(Wf[(q*3+2)*LAT + l], h, f2a);
    }
    #pragma unroll
    for (int m = 1; m <= 4; m <<= 1) {
        wa  += __shfl_xor(wa,  m, 64);
        sa  += __shfl_xor(sa,  m, 64);
        f0a += __shfl_xor(f0a, m, 64);
        f1a += __shfl_xor(f1a, m, 64);
        f2a += __shfl_xor(f2a, m, 64);
    }
    float w  = softplus_f(wa  + bw[q]);
    float s  = softplus_f(sa  + bs[q]);
    float f0 = softplus_f(f0a + bf[q*3+0]);
    float f1 = softplus_f(f1a + bf[q*3+1]);
    float f2 = softplus_f(f2a + bf[q*3+2]);
    float phase = f0*p0 + f1*p1 + f2*p2;
    float fr = phase - floorf(phase);
    float sn = __builtin_amdgcn_sinf(fr);
    float cs = __builtin_amdgcn_cosf(fr);
    float a  = w * 1.1892071150027210f * sqrtf(s);
    if (c == 0) {
        F[0*FSTRIDE + q*NPTS + i] = a * cs;
        F[1*FSTRIDE + q*NPTS + i] = a * sn;
        F[2*FSTRIDE + q*NPTS + i] = s * s;
    }
}

// pair v8: R19 EXACTLY, except the q-loop is now FULLY UNROLLED (the
// `#pragma unroll 1` carried since R4 forbade the scheduler from pipelining
// the 6 dependent ds_reads of q+1 under q's rcp/exp2 chain). VGPR headroom:
// 28 -> ~100 under the (256,4) 128-reg budget, no spill expected.
__global__ __launch_bounds__(256, 4) void pair_kernel(
    const float* __restrict__ x, const float* __restrict__ y,
    const float* __restrict__ FX, const float* __restrict__ FY,
    float* __restrict__ K)
{
    __shared__ float lfi[3][QQ][32];
    __shared__ float lpi[3][32];
    __shared__ float lfj[2][3][QQ][64];
    __shared__ float lpj[2][3][64];

    const int t  = threadIdx.x;
    const int tx = t & 31;
    const int ty = t >> 5;
    const int i0 = (blockIdx.x >> 4) * 32;
    const int jb = (blockIdx.x & 15) * 128;

    // ---- stage everything (i-side + both j-tiles), single barrier ----
    #pragma unroll
    for (int k = 0; k < 3; ++k) {
        int idx = t + k * 256;
        int f = idx >> 8, rem = idx & 255, q = rem >> 5, ii = rem & 31;
        lfi[f][q][ii] = FX[f*FSTRIDE + q*NPTS + i0 + ii];
    }
    #pragma unroll
    for (int k = 0; k < 6; ++k) {
        int idx = t + k * 256;
        int f = idx >> 9, q = (idx >> 6) & 7, jj = idx & 63;
        lfj[0][f][q][jj] = FY[f*FSTRIDE + q*NPTS + jb + jj];
        lfj[1][f][q][jj] = FY[f*FSTRIDE + q*NPTS + jb + 64 + jj];
    }
    if (t < 96) {
        int d = t >> 5, ii = t & 31;
        lpi[d][ii] = x[(i0 + ii)*3 + d] * SQRT_LOG2E;
    }
    if (t < 192) {
        int d = t >> 6, jj = t & 63;
        lpj[0][d][jj] = y[(jb + jj)*3 + d] * SQRT_LOG2E;
        lpj[1][d][jj] = y[(jb + 64 + jj)*3 + d] * SQRT_LOG2E;
    }
    __syncthreads();

    float4 xi0 = *(const float4*)&lpi[0][ty*4];
    float4 xi1 = *(const float4*)&lpi[1][ty*4];
    float4 xi2 = *(const float4*)&lpi[2][ty*4];
    float xs0[4] = {xi0.x, xi0.y, xi0.z, xi0.w};
    float xs1[4] = {xi1.x, xi1.y, xi1.z, xi1.w};
    float xs2[4] = {xi2.x, xi2.y, xi2.z, xi2.w};

    #pragma unroll 1
    for (int tile = 0; tile < 2; ++tile) {
        const int j0 = jb + tile * 64;

        v2f yj0 = *(const v2f*)&lpj[tile][0][tx*2];
        v2f yj1 = *(const v2f*)&lpj[tile][1][tx*2];
        v2f yj2 = *(const v2f*)&lpj[tile][2][tx*2];

        v2f d2n[4];
        #pragma unroll
        for (int ii = 0; ii < 4; ++ii) {
            v2f dx = xs0[ii] - yj0;
            v2f dy = xs1[ii] - yj1;
            v2f dz = xs2[ii] - yj2;
            d2n[ii] = -(dx*dx + dy*dy + dz*dz);
        }

        v2f acc[4] = {};
        #pragma unroll
        for (int q = 0; q < QQ; ++q) {
            float4 cai4 = *(const float4*)&lfi[0][q][ty*4];
            float4 sai4 = *(const float4*)&lfi[1][q][ty*4];
            float4 s2i4 = *(const float4*)&lfi[2][q][ty*4];
            v2f caj = *(const v2f*)&lfj[tile][0][q][tx*2];
            v2f saj = *(const v2f*)&lfj[tile][1][q][tx*2];
            v2f s2j = *(const v2f*)&lfj[tile][2][q][tx*2];
            float cai[4] = {cai4.x, cai4.y, cai4.z, cai4.w};
            float sai[4] = {sai4.x, sai4.y, sai4.z, sai4.w};
            float s2i[4] = {s2i4.x, s2i4.y, s2i4.z, s2i4.w};
            #pragma unroll
            for (int ii = 0; ii < 4; ++ii) {
                v2f s2  = s2i[ii] + s2j;
                v2f inv = { __builtin_amdgcn_rcpf(s2.x), __builtin_amdgcn_rcpf(s2.y) };
                v2f tt  = d2n[ii] * inv;
                v2f e   = { exp2_fast(tt.x), exp2_fast(tt.y) };
                v2f ct  = cai[ii]*caj + sai[ii]*saj;
                acc[ii] += (inv * e) * ct;
            }
        }

        #pragma unroll
        for (int ii = 0; ii < 4; ++ii) {
            int i = i0 + ty*4 + ii;
            float2 o = make_float2(acc[ii].x, acc[ii].y);
            __builtin_nontemporal_store(*(const unsigned long long*)&o,
                (unsigned long long*)&K[(size_t)i * NPTS + j0 + tx*2]);
        }
    }
}

extern "C" void kernel_launch(void* const* d_in, const int* in_sizes, int n_in,
                              void* d_out, int out_size, void* d_ws, size_t ws_size,
                              hipStream_t stream) {
    const float* x  = (const float*)d_in[0];
    const float* y  = (const float*)d_in[1];
    const float* W1 = (const float*)d_in[2];
    const float* b1 = (const float*)d_in[3];
    const float* Ww = (const float*)d_in[4];
    const float* bw = (const float*)d_in[5];
    const float* Wf = (const float*)d_in[6];
    const float* bf = (const float*)d_in[7];
    const float* Ws = (const float*)d_in[8];
    const float* bs = (const float*)d_in[9];
    float* K = (float*)d_out;

    float* FX = (float*)d_ws;
    float* FY = FX + 3 * FSTRIDE;

    feat_kernel<<<1024, 256, 0, stream>>>(x, y, W1, b1, Ww, bw, Wf, bf, Ws, bs, FX, FY);

    pair_kernel<<<1024, 256, 0, stream>>>(x, y, FX, FY, K);
}

// Round 21
// 21.964 us; speedup vs baseline: 3.5990x; 3.5990x over previous
//
#include <hip/hip_runtime.h>
#include <math.h>

#define NPTS 2048
#define QQ 8
#define LAT 64
#define LOG2E 1.4426950408889634f
#define SQRT_LOG2E 1.2011224087864498f
#define LN2 0.6931471805599453f
#define FSTRIDE (QQ * NPTS)

typedef float v2f __attribute__((ext_vector_type(2)));

__device__ __forceinline__ float exp2_fast(float v) { return __builtin_amdgcn_exp2f(v); }
__device__ __forceinline__ float log2_fast(float v) { return __builtin_amdgcn_logf(v); }

__device__ __forceinline__ float softplus_f(float v) {
    return fmaxf(v, 0.f) + LN2 * log2_fast(1.f + exp2_fast(-fabsf(v) * LOG2E));
}

// feat (R10, unchanged): one point per wave, no LDS, no barriers.
__global__ __launch_bounds__(256) void feat_kernel(
    const float* __restrict__ x, const float* __restrict__ y,
    const float* __restrict__ W1, const float* __restrict__ b1,
    const float* __restrict__ Ww, const float* __restrict__ bw,
    const float* __restrict__ Wf, const float* __restrict__ bf,
    const float* __restrict__ Ws, const float* __restrict__ bs,
    float* __restrict__ FX, float* __restrict__ FY)
{
    const int t    = threadIdx.x;
    const int wv   = t >> 6;
    const int lane = t & 63;
    const int c    = lane & 7;
    const int q    = lane >> 3;
    const int bid  = blockIdx.x;
    const int side = bid >> 9;
    const int i    = (bid & 511) * 4 + wv;
    const float* P = side ? y : x;
    float* F = side ? FY : FX;

    const float p0 = P[i*3+0], p1 = P[i*3+1], p2 = P[i*3+2];
    const float lam = 1.0507009873554805f, lamalf = 1.7580993408473766f;

    float wa = 0.f, sa = 0.f, f0a = 0.f, f1a = 0.f, f2a = 0.f;
    #pragma unroll
    for (int it = 0; it < 8; ++it) {
        int l = it*8 + c;
        float v = fmaf(W1[l*3+0], p0, fmaf(W1[l*3+1], p1, fmaf(W1[l*3+2], p2, b1[l])));
        float e = exp2_fast(v * LOG2E);
        float h = v > 0.f ? lam * v : lamalf * (e - 1.f);
        wa  = fmaf(Ww[q*LAT + l],       h, wa);
        sa  = fmaf(Ws[q*LAT + l],       h, sa);
        f0a = fmaf(Wf[(q*3+0)*LAT + l], h, f0a);
        f1a = fmaf(Wf[(q*3+1)*LAT + l], h, f1a);
        f2a = fmaf(Wf[(q*3+2)*LAT + l], h, f2a);
    }
    #pragma unroll
    for (int m = 1; m <= 4; m <<= 1) {
        wa  += __shfl_xor(wa,  m, 64);
        sa  += __shfl_xor(sa,  m, 64);
        f0a += __shfl_xor(f0a, m, 64);
        f1a += __shfl_xor(f1a, m, 64);
        f2a += __shfl_xor(f2a, m, 64);
    }
    float w  = softplus_f(wa  + bw[q]);
    float s  = softplus_f(sa  + bs[q]);
    float f0 = softplus_f(f0a + bf[q*3+0]);
    float f1 = softplus_f(f1a + bf[q*3+1]);
    float f2 = softplus_f(f2a + bf[q*3+2]);
    float phase = f0*p0 + f1*p1 + f2*p2;
    float fr = phase - floorf(phase);
    float sn = __builtin_amdgcn_sinf(fr);
    float cs = __builtin_amdgcn_cosf(fr);
    float a  = w * 1.1892071150027210f * sqrtf(s);
    if (c == 0) {
        F[0*FSTRIDE + q*NPTS + i] = a * cs;
        F[1*FSTRIDE + q*NPTS + i] = a * sn;
        F[2*FSTRIDE + q*NPTS + i] = s * s;
    }
}

// pair v9: R19 exactly, except `#pragma unroll 2` on the q-loop — the
// minimal form of R20's cross-q pipelining theory that fits registers
// (R20's full unroll spilled: FETCH 143MB, 71us). +~24 live regs, ~70 total.
__global__ __launch_bounds__(256, 4) void pair_kernel(
    const float* __restrict__ x, const float* __restrict__ y,
    const float* __restrict__ FX, const float* __restrict__ FY,
    float* __restrict__ K)
{
    __shared__ float lfi[3][QQ][32];
    __shared__ float lpi[3][32];
    __shared__ float lfj[2][3][QQ][64];
    __shared__ float lpj[2][3][64];

    const int t  = threadIdx.x;
    const int tx = t & 31;
    const int ty = t >> 5;
    const int i0 = (blockIdx.x >> 4) * 32;
    const int jb = (blockIdx.x & 15) * 128;

    // ---- stage everything (i-side + both j-tiles), single barrier ----
    #pragma unroll
    for (int k = 0; k < 3; ++k) {
        int idx = t + k * 256;
        int f = idx >> 8, rem = idx & 255, q = rem >> 5, ii = rem & 31;
        lfi[f][q][ii] = FX[f*FSTRIDE + q*NPTS + i0 + ii];
    }
    #pragma unroll
    for (int k = 0; k < 6; ++k) {
        int idx = t + k * 256;
        int f = idx >> 9, q = (idx >> 6) & 7, jj = idx & 63;
        lfj[0][f][q][jj] = FY[f*FSTRIDE + q*NPTS + jb + jj];
        lfj[1][f][q][jj] = FY[f*FSTRIDE + q*NPTS + jb + 64 + jj];
    }
    if (t < 96) {
        int d = t >> 5, ii = t & 31;
        lpi[d][ii] = x[(i0 + ii)*3 + d] * SQRT_LOG2E;
    }
    if (t < 192) {
        int d = t >> 6, jj = t & 63;
        lpj[0][d][jj] = y[(jb + jj)*3 + d] * SQRT_LOG2E;
        lpj[1][d][jj] = y[(jb + 64 + jj)*3 + d] * SQRT_LOG2E;
    }
    __syncthreads();

    float4 xi0 = *(const float4*)&lpi[0][ty*4];
    float4 xi1 = *(const float4*)&lpi[1][ty*4];
    float4 xi2 = *(const float4*)&lpi[2][ty*4];
    float xs0[4] = {xi0.x, xi0.y, xi0.z, xi0.w};
    float xs1[4] = {xi1.x, xi1.y, xi1.z, xi1.w};
    float xs2[4] = {xi2.x, xi2.y, xi2.z, xi2.w};

    #pragma unroll 1
    for (int tile = 0; tile < 2; ++tile) {
        const int j0 = jb + tile * 64;

        v2f yj0 = *(const v2f*)&lpj[tile][0][tx*2];
        v2f yj1 = *(const v2f*)&lpj[tile][1][tx*2];
        v2f yj2 = *(const v2f*)&lpj[tile][2][tx*2];

        v2f d2n[4];
        #pragma unroll
        for (int ii = 0; ii < 4; ++ii) {
            v2f dx = xs0[ii] - yj0;
            v2f dy = xs1[ii] - yj1;
            v2f dz = xs2[ii] - yj2;
            d2n[ii] = -(dx*dx + dy*dy + dz*dz);
        }

        v2f acc[4] = {};
        #pragma unroll 2
        for (int q = 0; q < QQ; ++q) {
            float4 cai4 = *(const float4*)&lfi[0][q][ty*4];
            float4 sai4 = *(const float4*)&lfi[1][q][ty*4];
            float4 s2i4 = *(const float4*)&lfi[2][q][ty*4];
            v2f caj = *(const v2f*)&lfj[tile][0][q][tx*2];
            v2f saj = *(const v2f*)&lfj[tile][1][q][tx*2];
            v2f s2j = *(const v2f*)&lfj[tile][2][q][tx*2];
            float cai[4] = {cai4.x, cai4.y, cai4.z, cai4.w};
            float sai[4] = {sai4.x, sai4.y, sai4.z, sai4.w};
            float s2i[4] = {s2i4.x, s2i4.y, s2i4.z, s2i4.w};
            #pragma unroll
            for (int ii = 0; ii < 4; ++ii) {
                v2f s2  = s2i[ii] + s2j;
                v2f inv = { __builtin_amdgcn_rcpf(s2.x), __builtin_amdgcn_rcpf(s2.y) };
                v2f tt  = d2n[ii] * inv;
                v2f e   = { exp2_fast(tt.x), exp2_fast(tt.y) };
                v2f ct  = cai[ii]*caj + sai[ii]*saj;
                acc[ii] += (inv * e) * ct;
            }
        }

        #pragma unroll
        for (int ii = 0; ii < 4; ++ii) {
            int i = i0 + ty*4 + ii;
            float2 o = make_float2(acc[ii].x, acc[ii].y);
            __builtin_nontemporal_store(*(const unsigned long long*)&o,
                (unsigned long long*)&K[(size_t)i * NPTS + j0 + tx*2]);
        }
    }
}

extern "C" void kernel_launch(void* const* d_in, const int* in_sizes, int n_in,
                              void* d_out, int out_size, void* d_ws, size_t ws_size,
                              hipStream_t stream) {
    const float* x  = (const float*)d_in[0];
    const float* y  = (const float*)d_in[1];
    const float* W1 = (const float*)d_in[2];
    const float* b1 = (const float*)d_in[3];
    const float* Ww = (const float*)d_in[4];
    const float* bw = (const float*)d_in[5];
    const float* Wf = (const float*)d_in[6];
    const float* bf = (const float*)d_in[7];
    const float* Ws = (const float*)d_in[8];
    const float* bs = (const float*)d_in[9];
    float* K = (float*)d_out;

    float* FX = (float*)d_ws;
    float* FY = FX + 3 * FSTRIDE;

    feat_kernel<<<1024, 256, 0, stream>>>(x, y, W1, b1, Ww, bw, Wf, bf, Ws, bs, FX, FY);

    pair_kernel<<<1024, 256, 0, stream>>>(x, y, FX, FY, K);
}

// Round 22
// 21.791 us; speedup vs baseline: 3.6276x; 1.0079x over previous
//
#include <hip/hip_runtime.h>
#include <math.h>

#define NPTS 2048
#define QQ 8
#define LAT 64
#define LOG2E 1.4426950408889634f
#define SQRT_LOG2E 1.2011224087864498f
#define LN2 0.6931471805599453f
#define FSTRIDE (QQ * NPTS)

typedef float v2f __attribute__((ext_vector_type(2)));

__device__ __forceinline__ float exp2_fast(float v) { return __builtin_amdgcn_exp2f(v); }
__device__ __forceinline__ float log2_fast(float v) { return __builtin_amdgcn_logf(v); }

__device__ __forceinline__ float softplus_f(float v) {
    return fmaxf(v, 0.f) + LN2 * log2_fast(1.f + exp2_fast(-fabsf(v) * LOG2E));
}

// feat (R10, unchanged): one point per wave, no LDS, no barriers.
__global__ __launch_bounds__(256) void feat_kernel(
    const float* __restrict__ x, const float* __restrict__ y,
    const float* __restrict__ W1, const float* __restrict__ b1,
    const float* __restrict__ Ww, const float* __restrict__ bw,
    const float* __restrict__ Wf, const float* __restrict__ bf,
    const float* __restrict__ Ws, const float* __restrict__ bs,
    float* __restrict__ FX, float* __restrict__ FY)
{
    const int t    = threadIdx.x;
    const int wv   = t >> 6;
    const int lane = t & 63;
    const int c    = lane & 7;
    const int q    = lane >> 3;
    const int bid  = blockIdx.x;
    const int side = bid >> 9;
    const int i    = (bid & 511) * 4 + wv;
    const float* P = side ? y : x;
    float* F = side ? FY : FX;

    const float p0 = P[i*3+0], p1 = P[i*3+1], p2 = P[i*3+2];
    const float lam = 1.0507009873554805f, lamalf = 1.7580993408473766f;

    float wa = 0.f, sa = 0.f, f0a = 0.f, f1a = 0.f, f2a = 0.f;
    #pragma unroll
    for (int it = 0; it < 8; ++it) {
        int l = it*8 + c;
        float v = fmaf(W1[l*3+0], p0, fmaf(W1[l*3+1], p1, fmaf(W1[l*3+2], p2, b1[l])));
        float e = exp2_fast(v * LOG2E);
        float h = v > 0.f ? lam * v : lamalf * (e - 1.f);
        wa  = fmaf(Ww[q*LAT + l],       h, wa);
        sa  = fmaf(Ws[q*LAT + l],       h, sa);
        f0a = fmaf(Wf[(q*3+0)*LAT + l], h, f0a);
        f1a = fmaf(Wf[(q*3+1)*LAT + l], h, f1a);
        f2a = fmaf(Wf[(q*3+2)*LAT + l], h, f2a);
    }
    #pragma unroll
    for (int m = 1; m <= 4; m <<= 1) {
        wa  += __shfl_xor(wa,  m, 64);
        sa  += __shfl_xor(sa,  m, 64);
        f0a += __shfl_xor(f0a, m, 64);
        f1a += __shfl_xor(f1a, m, 64);
        f2a += __shfl_xor(f2a, m, 64);
    }
    float w  = softplus_f(wa  + bw[q]);
    float s  = softplus_f(sa  + bs[q]);
    float f0 = softplus_f(f0a + bf[q*3+0]);
    float f1 = softplus_f(f1a + bf[q*3+1]);
    float f2 = softplus_f(f2a + bf[q*3+2]);
    float phase = f0*p0 + f1*p1 + f2*p2;
    float fr = phase - floorf(phase);
    float sn = __builtin_amdgcn_sinf(fr);
    float cs = __builtin_amdgcn_cosf(fr);
    float a  = w * 1.1892071150027210f * sqrtf(s);
    if (c == 0) {
        F[0*FSTRIDE + q*NPTS + i] = a * cs;
        F[1*FSTRIDE + q*NPTS + i] = a * sn;
        F[2*FSTRIDE + q*NPTS + i] = s * s;
    }
}

// pair v10: Q-OUTER / TILE-INNER. The q-loop is LDS-pipe-bound (model vs
// R11 counters: LDS 92% occupied, VALU 80%); tile-outer read the i-side
// features TWICE (12 LDS reads/q across tiles). q-outer reads them once:
// 9 reads/q = 30% LDS cut -> VALU becomes the bound. acc for both tiles
// stays live (+16 regs, ~104 total under the (256,4) 128-reg budget).
// Inner math byte-identical to R21.
__global__ __launch_bounds__(256, 4) void pair_kernel(
    const float* __restrict__ x, const float* __restrict__ y,
    const float* __restrict__ FX, const float* __restrict__ FY,
    float* __restrict__ K)
{
    __shared__ float lfi[3][QQ][32];
    __shared__ float lpi[3][32];
    __shared__ float lfj[2][3][QQ][64];
    __shared__ float lpj[2][3][64];

    const int t  = threadIdx.x;
    const int tx = t & 31;
    const int ty = t >> 5;
    const int i0 = (blockIdx.x >> 4) * 32;
    const int jb = (blockIdx.x & 15) * 128;

    // ---- stage everything (i-side + both j-tiles), single barrier ----
    #pragma unroll
    for (int k = 0; k < 3; ++k) {
        int idx = t + k * 256;
        int f = idx >> 8, rem = idx & 255, q = rem >> 5, ii = rem & 31;
        lfi[f][q][ii] = FX[f*FSTRIDE + q*NPTS + i0 + ii];
    }
    #pragma unroll
    for (int k = 0; k < 6; ++k) {
        int idx = t + k * 256;
        int f = idx >> 9, q = (idx >> 6) & 7, jj = idx & 63;
        lfj[0][f][q][jj] = FY[f*FSTRIDE + q*NPTS + jb + jj];
        lfj[1][f][q][jj] = FY[f*FSTRIDE + q*NPTS + jb + 64 + jj];
    }
    if (t < 96) {
        int d = t >> 5, ii = t & 31;
        lpi[d][ii] = x[(i0 + ii)*3 + d] * SQRT_LOG2E;
    }
    if (t < 192) {
        int d = t >> 6, jj = t & 63;
        lpj[0][d][jj] = y[(jb + jj)*3 + d] * SQRT_LOG2E;
        lpj[1][d][jj] = y[(jb + 64 + jj)*3 + d] * SQRT_LOG2E;
    }
    __syncthreads();

    float4 xi0 = *(const float4*)&lpi[0][ty*4];
    float4 xi1 = *(const float4*)&lpi[1][ty*4];
    float4 xi2 = *(const float4*)&lpi[2][ty*4];
    float xs0[4] = {xi0.x, xi0.y, xi0.z, xi0.w};
    float xs1[4] = {xi1.x, xi1.y, xi1.z, xi1.w};
    float xs2[4] = {xi2.x, xi2.y, xi2.z, xi2.w};

    // d2n for BOTH tiles up front (held in registers).
    v2f d2nA[4], d2nB[4];
    {
        v2f ya0 = *(const v2f*)&lpj[0][0][tx*2];
        v2f ya1 = *(const v2f*)&lpj[0][1][tx*2];
        v2f ya2 = *(const v2f*)&lpj[0][2][tx*2];
        v2f yb0 = *(const v2f*)&lpj[1][0][tx*2];
        v2f yb1 = *(const v2f*)&lpj[1][1][tx*2];
        v2f yb2 = *(const v2f*)&lpj[1][2][tx*2];
        #pragma unroll
        for (int ii = 0; ii < 4; ++ii) {
            v2f dxa = xs0[ii] - ya0, dya = xs1[ii] - ya1, dza = xs2[ii] - ya2;
            d2nA[ii] = -(dxa*dxa + dya*dya + dza*dza);
            v2f dxb = xs0[ii] - yb0, dyb = xs1[ii] - yb1, dzb = xs2[ii] - yb2;
            d2nB[ii] = -(dxb*dxb + dyb*dyb + dzb*dzb);
        }
    }

    v2f accA[4] = {}, accB[4] = {};
    #pragma unroll 2
    for (int q = 0; q < QQ; ++q) {
        // i-side: read ONCE per q (was twice in tile-outer form)
        float4 cai4 = *(const float4*)&lfi[0][q][ty*4];
        float4 sai4 = *(const float4*)&lfi[1][q][ty*4];
        float4 s2i4 = *(const float4*)&lfi[2][q][ty*4];
        float cai[4] = {cai4.x, cai4.y, cai4.z, cai4.w};
        float sai[4] = {sai4.x, sai4.y, sai4.z, sai4.w};
        float s2i[4] = {s2i4.x, s2i4.y, s2i4.z, s2i4.w};

        // tile A
        {
            v2f caj = *(const v2f*)&lfj[0][0][q][tx*2];
            v2f saj = *(const v2f*)&lfj[0][1][q][tx*2];
            v2f s2j = *(const v2f*)&lfj[0][2][q][tx*2];
            #pragma unroll
            for (int ii = 0; ii < 4; ++ii) {
                v2f s2  = s2i[ii] + s2j;
                v2f inv = { __builtin_amdgcn_rcpf(s2.x), __builtin_amdgcn_rcpf(s2.y) };
                v2f tt  = d2nA[ii] * inv;
                v2f e   = { exp2_fast(tt.x), exp2_fast(tt.y) };
                v2f ct  = cai[ii]*caj + sai[ii]*saj;
                accA[ii] += (inv * e) * ct;
            }
        }
        // tile B
        {
            v2f caj = *(const v2f*)&lfj[1][0][q][tx*2];
            v2f saj = *(const v2f*)&lfj[1][1][q][tx*2];
            v2f s2j = *(const v2f*)&lfj[1][2][q][tx*2];
            #pragma unroll
            for (int ii = 0; ii < 4; ++ii) {
                v2f s2  = s2i[ii] + s2j;
                v2f inv = { __builtin_amdgcn_rcpf(s2.x), __builtin_amdgcn_rcpf(s2.y) };
                v2f tt  = d2nB[ii] * inv;
                v2f e   = { exp2_fast(tt.x), exp2_fast(tt.y) };
                v2f ct  = cai[ii]*caj + sai[ii]*saj;
                accB[ii] += (inv * e) * ct;
            }
        }
    }

    #pragma unroll
    for (int ii = 0; ii < 4; ++ii) {
        int i = i0 + ty*4 + ii;
        float2 oa = make_float2(accA[ii].x, accA[ii].y);
        __builtin_nontemporal_store(*(const unsigned long long*)&oa,
            (unsigned long long*)&K[(size_t)i * NPTS + jb + tx*2]);
        float2 ob = make_float2(accB[ii].x, accB[ii].y);
        __builtin_nontemporal_store(*(const unsigned long long*)&ob,
            (unsigned long long*)&K[(size_t)i * NPTS + jb + 64 + tx*2]);
    }
}

extern "C" void kernel_launch(void* const* d_in, const int* in_sizes, int n_in,
                              void* d_out, int out_size, void* d_ws, size_t ws_size,
                              hipStream_t stream) {
    const float* x  = (const float*)d_in[0];
    const float* y  = (const float*)d_in[1];
    const float* W1 = (const float*)d_in[2];
    const float* b1 = (const float*)d_in[3];
    const float* Ww = (const float*)d_in[4];
    const float* bw = (const float*)d_in[5];
    const float* Wf = (const float*)d_in[6];
    const float* bf = (const float*)d_in[7];
    const float* Ws = (const float*)d_in[8];
    const float* bs = (const float*)d_in[9];
    float* K = (float*)d_out;

    float* FX = (float*)d_ws;
    float* FY = FX + 3 * FSTRIDE;

    feat_kernel<<<1024, 256, 0, stream>>>(x, y, W1, b1, Ww, bw, Wf, bf, Ws, bs, FX, FY);

    pair_kernel<<<1024, 256, 0, stream>>>(x, y, FX, FY, K);
}

// Round 24
// 21.751 us; speedup vs baseline: 3.6343x; 1.0019x over previous
//
#include <hip/hip_runtime.h>
#include <math.h>

#define NPTS 2048
#define QQ 8
#define LAT 64
#define LOG2E 1.4426950408889634f
#define SQRT_LOG2E 1.2011224087864498f
#define LN2 0.6931471805599453f
#define FSTRIDE (QQ * NPTS)

typedef float v2f __attribute__((ext_vector_type(2)));
typedef float v4f __attribute__((ext_vector_type(4)));

__device__ __forceinline__ float exp2_fast(float v) { return __builtin_amdgcn_exp2f(v); }
__device__ __forceinline__ float log2_fast(float v) { return __builtin_amdgcn_logf(v); }

__device__ __forceinline__ float softplus_f(float v) {
    return fmaxf(v, 0.f) + LN2 * log2_fast(1.f + exp2_fast(-fabsf(v) * LOG2E));
}

// feat (R10, unchanged): one point per wave, no LDS, no barriers.
__global__ __launch_bounds__(256) void feat_kernel(
    const float* __restrict__ x, const float* __restrict__ y,
    const float* __restrict__ W1, const float* __restrict__ b1,
    const float* __restrict__ Ww, const float* __restrict__ bw,
    const float* __restrict__ Wf, const float* __restrict__ bf,
    const float* __restrict__ Ws, const float* __restrict__ bs,
    float* __restrict__ FX, float* __restrict__ FY)
{
    const int t    = threadIdx.x;
    const int wv   = t >> 6;
    const int lane = t & 63;
    const int c    = lane & 7;
    const int q    = lane >> 3;
    const int bid  = blockIdx.x;
    const int side = bid >> 9;
    const int i    = (bid & 511) * 4 + wv;
    const float* P = side ? y : x;
    float* F = side ? FY : FX;

    const float p0 = P[i*3+0], p1 = P[i*3+1], p2 = P[i*3+2];
    const float lam = 1.0507009873554805f, lamalf = 1.7580993408473766f;

    float wa = 0.f, sa = 0.f, f0a = 0.f, f1a = 0.f, f2a = 0.f;
    #pragma unroll
    for (int it = 0; it < 8; ++it) {
        int l = it*8 + c;
        float v = fmaf(W1[l*3+0], p0, fmaf(W1[l*3+1], p1, fmaf(W1[l*3+2], p2, b1[l])));
        float e = exp2_fast(v * LOG2E);
        float h = v > 0.f ? lam * v : lamalf * (e - 1.f);
        wa  = fmaf(Ww[q*LAT + l],       h, wa);
        sa  = fmaf(Ws[q*LAT + l],       h, sa);
        f0a = fmaf(Wf[(q*3+0)*LAT + l], h, f0a);
        f1a = fmaf(Wf[(q*3+1)*LAT + l], h, f1a);
        f2a = fmaf(Wf[(q*3+2)*LAT + l], h, f2a);
    }
    #pragma unroll
    for (int m = 1; m <= 4; m <<= 1) {
        wa  += __shfl_xor(wa,  m, 64);
        sa  += __shfl_xor(sa,  m, 64);
        f0a += __shfl_xor(f0a, m, 64);
        f1a += __shfl_xor(f1a, m, 64);
        f2a += __shfl_xor(f2a, m, 64);
    }
    float w  = softplus_f(wa  + bw[q]);
    float s  = softplus_f(sa  + bs[q]);
    float f0 = softplus_f(f0a + bf[q*3+0]);
    float f1 = softplus_f(f1a + bf[q*3+1]);
    float f2 = softplus_f(f2a + bf[q*3+2]);
    float phase = f0*p0 + f1*p1 + f2*p2;
    float fr = phase - floorf(phase);
    float sn = __builtin_amdgcn_sinf(fr);
    float cs = __builtin_amdgcn_cosf(fr);
    float a  = w * 1.1892071150027210f * sqrtf(s);
    if (c == 0) {
        F[0*FSTRIDE + q*NPTS + i] = a * cs;
        F[1*FSTRIDE + q*NPTS + i] = a * sn;
        F[2*FSTRIDE + q*NPTS + i] = s * s;
    }
}

// pair v11b: single 128-wide j-tile, v4f j-fragments (4i x 4j per thread).
// vs R22: LDS/q 84->72cy (j-side 6xb64 -> 3xb128), one ct codepath, stores
// 1x NT b128 per row (via clang ext-vector v4f — HIP float4 is rejected by
// __builtin_nontemporal_store, R23 compile error). 1024 blocks, q-outer,
// unroll 2.
__global__ __launch_bounds__(256, 4) void pair_kernel(
    const float* __restrict__ x, const float* __restrict__ y,
    const float* __restrict__ FX, const float* __restrict__ FY,
    float* __restrict__ K)
{
    __shared__ float lfi[3][QQ][32];    // 3 KiB
    __shared__ float lpi[3][32];        // 384 B
    __shared__ float lfj[3][QQ][128];   // 12 KiB
    __shared__ float lpj[3][128];       // 1.5 KiB

    const int t  = threadIdx.x;
    const int tx = t & 31;              // 4 j-cols each (tx*4)
    const int ty = t >> 5;              // 4 i-rows each (ty*4)
    const int i0 = (blockIdx.x >> 4) * 32;
    const int jb = (blockIdx.x & 15) * 128;

    // ---- stage: i-side 768 floats, j-side 3072 floats, positions ----
    #pragma unroll
    for (int k = 0; k < 3; ++k) {
        int idx = t + k * 256;
        int f = idx >> 8, rem = idx & 255, q = rem >> 5, ii = rem & 31;
        lfi[f][q][ii] = FX[f*FSTRIDE + q*NPTS + i0 + ii];
    }
    #pragma unroll
    for (int k = 0; k < 12; ++k) {
        int idx = t + k * 256;              // 0..3071
        int f = idx >> 10, rem = idx & 1023, q = rem >> 7, jj = rem & 127;
        lfj[f][q][jj] = FY[f*FSTRIDE + q*NPTS + jb + jj];
    }
    if (t < 96) {
        int d = t >> 5, ii = t & 31;
        lpi[d][ii] = x[(i0 + ii)*3 + d] * SQRT_LOG2E;
    }
    #pragma unroll
    for (int k = 0; k < 2; ++k) {
        int u = t + k * 256;
        if (u < 384) {
            int d = u >> 7, jj = u & 127;
            lpj[d][jj] = y[(jb + jj)*3 + d] * SQRT_LOG2E;
        }
    }
    __syncthreads();

    float4 xi0 = *(const float4*)&lpi[0][ty*4];
    float4 xi1 = *(const float4*)&lpi[1][ty*4];
    float4 xi2 = *(const float4*)&lpi[2][ty*4];
    float xs0[4] = {xi0.x, xi0.y, xi0.z, xi0.w};
    float xs1[4] = {xi1.x, xi1.y, xi1.z, xi1.w};
    float xs2[4] = {xi2.x, xi2.y, xi2.z, xi2.w};

    v4f yj0 = *(const v4f*)&lpj[0][tx*4];
    v4f yj1 = *(const v4f*)&lpj[1][tx*4];
    v4f yj2 = *(const v4f*)&lpj[2][tx*4];

    v4f d2n[4];
    #pragma unroll
    for (int ii = 0; ii < 4; ++ii) {
        v4f dx = xs0[ii] - yj0;
        v4f dy = xs1[ii] - yj1;
        v4f dz = xs2[ii] - yj2;
        d2n[ii] = -(dx*dx + dy*dy + dz*dz);
    }

    v4f acc[4] = {};
    #pragma unroll 2
    for (int q = 0; q < QQ; ++q) {
        float4 cai4 = *(const float4*)&lfi[0][q][ty*4];
        float4 sai4 = *(const float4*)&lfi[1][q][ty*4];
        float4 s2i4 = *(const float4*)&lfi[2][q][ty*4];
        v4f caj = *(const v4f*)&lfj[0][q][tx*4];
        v4f saj = *(const v4f*)&lfj[1][q][tx*4];
        v4f s2j = *(const v4f*)&lfj[2][q][tx*4];
        float cai[4] = {cai4.x, cai4.y, cai4.z, cai4.w};
        float sai[4] = {sai4.x, sai4.y, sai4.z, sai4.w};
        float s2i[4] = {s2i4.x, s2i4.y, s2i4.z, s2i4.w};
        #pragma unroll
        for (int ii = 0; ii < 4; ++ii) {
            v4f s2  = s2i[ii] + s2j;
            v4f inv = { __builtin_amdgcn_rcpf(s2.x), __builtin_amdgcn_rcpf(s2.y),
                        __builtin_amdgcn_rcpf(s2.z), __builtin_amdgcn_rcpf(s2.w) };
            v4f tt  = d2n[ii] * inv;
            v4f e   = { exp2_fast(tt.x), exp2_fast(tt.y),
                        exp2_fast(tt.z), exp2_fast(tt.w) };
            v4f ct  = cai[ii]*caj + sai[ii]*saj;
            acc[ii] += (inv * e) * ct;
        }
    }

    #pragma unroll
    for (int ii = 0; ii < 4; ++ii) {
        int i = i0 + ty*4 + ii;
        __builtin_nontemporal_store(acc[ii], (v4f*)&K[(size_t)i * NPTS + jb + tx*4]);
    }
}

extern "C" void kernel_launch(void* const* d_in, const int* in_sizes, int n_in,
                              void* d_out, int out_size, void* d_ws, size_t ws_size,
                              hipStream_t stream) {
    const float* x  = (const float*)d_in[0];
    const float* y  = (const float*)d_in[1];
    const float* W1 = (const float*)d_in[2];
    const float* b1 = (const float*)d_in[3];
    const float* Ww = (const float*)d_in[4];
    const float* bw = (const float*)d_in[5];
    const float* Wf = (const float*)d_in[6];
    const float* bf = (const float*)d_in[7];
    const float* Ws = (const float*)d_in[8];
    const float* bs = (const float*)d_in[9];
    float* K = (float*)d_out;

    float* FX = (float*)d_ws;
    float* FY = FX + 3 * FSTRIDE;

    feat_kernel<<<1024, 256, 0, stream>>>(x, y, W1, b1, Ww, bw, Wf, bf, Ws, bs, FX, FY);

    pair_kernel<<<1024, 256, 0, stream>>>(x, y, FX, FY, K);
}